// Round 2
// baseline (2430.410 us; speedup 1.0000x reference)
//
#include <hip/hip_runtime.h>
#include <cstdint>
#include <math.h>

#pragma clang fp contract(off)

typedef unsigned int u32;
typedef unsigned long long u64;

#define HFEAT 512
#define WFEAT 512
#define NPIX (HFEAT*WFEAT)          // 262144
#define TOPK 4000
#define IMG_SZ 16384.0f
#define NBUCKET 8192
#define CAP 32768

// ---- workspace layout (bytes) ----
#define WS_HIST 0                    // u32[8192]   32768
#define WS_META 32768                // u32[16]     64
#define WS_CKEY 32832                // u32[CAP]    131072
#define WS_CIDX 163904               // u32[CAP]    131072
#define WS_SEL  294976               // u32[TOPK]   16000
#define WS_NX1  310976               // f32[TOPK]
#define WS_NY1  326976
#define WS_NX2  342976
#define WS_NY2  358976
#define WS_NAR  374976
#define WS_VAL  390976               // u32[TOPK] -> end 406976

// f32 softmax over 2 logits, replicating numpy float32 op-for-op.
// exp computed in fp64 then rounded -> correctly-rounded f32 exp (matches glibc expf w.h.p.)
__device__ __forceinline__ void softmax2(float l0, float l1, float& s0, float& s1) {
    float m = fmaxf(l0, l1);
    float a0 = l0 - m;
    float a1 = l1 - m;
    float e0 = (float)::exp((double)a0);
    float e1 = (float)::exp((double)a1);
    float den = e0 + e1;
    s0 = e0 / den;
    s1 = e1 / den;
}

__global__ void k_zero(u32* ws32) {
    int t = blockIdx.x * blockDim.x + threadIdx.x;
    if (t < NBUCKET + 16) ws32[t] = 0;
}

// histogram of f32 score bits for score > 0.5; bucket = (bits - 0x3F000000) >> 10
__global__ void k_hist(const float* __restrict__ obj, u32* __restrict__ hist) {
    __shared__ u32 lh[NBUCKET];
    int tid = threadIdx.x;
    for (int b = tid; b < NBUCKET; b += 256) lh[b] = 0;
    __syncthreads();
    int p = blockIdx.x * 256 + tid;
    const float* o = obj + (size_t)p * 18;
#pragma unroll
    for (int k = 0; k < 9; ++k) {
        float s0, s1;
        softmax2(o[2*k], o[2*k+1], s0, s1);
        if (s1 > 0.5f) {
            u32 b = (__float_as_uint(s1) - 0x3F000000u) >> 10;
            atomicAdd(&lh[b], 1u);
        }
    }
    __syncthreads();
    for (int b = tid; b < NBUCKET; b += 256) {
        u32 c = lh[b];
        if (c) atomicAdd(&hist[b], c);
    }
}

// find threshold bucket: smallest B with count(bucket >= B) >= TOPK
__global__ void k_scan(const u32* __restrict__ hist, u32* __restrict__ meta) {
    __shared__ u32 ss[1024];
    int t = threadIdx.x;
    u32 local = 0;
#pragma unroll
    for (int j = 0; j < 8; ++j) local += hist[t*8 + j];
    ss[t] = local;
    __syncthreads();
    for (int off = 1; off < 1024; off <<= 1) {
        u32 v = (t + off < 1024) ? ss[t + off] : 0;
        __syncthreads();
        ss[t] += v;
        __syncthreads();
    }
    u32 S_t = ss[t];
    u32 S_next = (t < 1023) ? ss[t+1] : 0;
    if (S_t >= TOPK && S_next < TOPK) {
        u32 cum = S_next;
        int bsel = t*8;
        for (int b = t*8 + 7; b >= t*8; --b) {
            cum += hist[b];
            if (cum >= TOPK) { bsel = b; break; }
        }
        meta[1] = (u32)bsel;
        meta[2] = cum;
    }
}

__global__ void k_compact(const float* __restrict__ obj, u32* __restrict__ meta,
                          u32* __restrict__ ckey, u32* __restrict__ cidx) {
    int p = blockIdx.x * 256 + threadIdx.x;
    u32 thr = 0x3F000000u + (meta[1] << 10);
    const float* o = obj + (size_t)p * 18;
#pragma unroll
    for (int k = 0; k < 9; ++k) {
        float s0, s1;
        softmax2(o[2*k], o[2*k+1], s0, s1);
        if (s1 > 0.5f) {
            u32 bits = __float_as_uint(s1);
            if (bits >= thr) {
                u32 pos = atomicAdd(&meta[0], 1u);
                if (pos < CAP) { ckey[pos] = bits; cidx[pos] = (u32)(p*9 + k); }
            }
        }
    }
}

#define RTILE 4096
// exact rank of each candidate: (score desc, idx asc); ranks form a permutation
__global__ void k_rank(const u32* __restrict__ meta, const u32* __restrict__ ckey,
                       const u32* __restrict__ cidx, u32* __restrict__ sel) {
    __shared__ u32 lk[RTILE];
    __shared__ u32 li[RTILE];
    int tid = threadIdx.x;
    u32 Mu = meta[0];
    int M = (int)(Mu < (u32)CAP ? Mu : (u32)CAP);
    for (int cb = blockIdx.x * 256; cb < M; cb += gridDim.x * 256) {
        int c = cb + tid;
        bool act = (c < M);
        u32 key = 0, idx = 0;
        if (act) { key = ckey[c]; idx = cidx[c]; }
        int rank = 0;
        for (int t0 = 0; t0 < M; t0 += RTILE) {
            int cnt = (M - t0 < RTILE) ? (M - t0) : RTILE;
            __syncthreads();
            for (int j = tid; j < cnt; j += 256) { lk[j] = ckey[t0+j]; li[j] = cidx[t0+j]; }
            __syncthreads();
            if (act) {
                for (int j = 0; j < cnt; ++j) {
                    u32 kj = lk[j];
                    rank += (kj > key || (kj == key && li[j] < idx)) ? 1 : 0;
                }
            }
        }
        if (act && rank < TOPK) sel[rank] = idx;
    }
}

__global__ void k_gather(const float* __restrict__ obj, const float* __restrict__ reg,
                         const float* __restrict__ anch, const u32* __restrict__ sel,
                         float* __restrict__ out,
                         float* __restrict__ nx1, float* __restrict__ ny1,
                         float* __restrict__ nx2, float* __restrict__ ny2,
                         float* __restrict__ nar, u32* __restrict__ valid) {
    int r = blockIdx.x * 256 + threadIdx.x;
    if (r >= TOPK) return;
    u32 i = sel[r];
    u32 p = i / 9u, k = i - p * 9u;
    float l0 = obj[(size_t)p*18 + 2*k];
    float l1 = obj[(size_t)p*18 + 2*k + 1];
    float s0, s1;
    softmax2(l0, l1, s0, s1);
    const float* rg = reg + (size_t)p*36 + 4*k;
    float t0 = rg[0], t1 = rg[1], t2 = rg[2], t3 = rg[3];
    const float* an = anch + (size_t)i*4;
    float a0 = an[0], a1 = an[1], a2 = an[2], a3 = an[3];
    float cx = a0 + a2/2.0f + t0*a2;           // ((a0 + a2/2) + t0*a2), no FMA
    float cy = a1 + a3/2.0f + t1*a3;
    float w = a2 * (float)::exp((double)t2);
    float h = a3 * (float)::exp((double)t3);
    float bx = cx - w/2.0f;
    float by = cy - h/2.0f;
    float x1 = fminf(fmaxf(bx, 0.0f), IMG_SZ);
    float y1 = fminf(fmaxf(by, 0.0f), IMG_SZ);
    float x2 = fminf(fmaxf(bx + w, 0.0f), IMG_SZ);
    float y2 = fminf(fmaxf(by + h, 0.0f), IMG_SZ);
    float bw = x2 - x1, bh = y2 - y1;
    out[4*r+0] = x1;
    out[4*r+1] = y1;
    out[4*r+2] = bw;
    out[4*r+3] = bh;
    out[16000 + 2*r]     = s0;
    out[16000 + 2*r + 1] = s1;
    nx1[r] = x1; ny1[r] = y1;
    nx2[r] = x1 + bw;                           // ref: x2 = x1 + b[:,2]
    ny2[r] = y1 + bh;
    nar[r] = bw * bh;                           // ref: area = b[:,2]*b[:,3]
    valid[r] = (s1 > 0.5f) ? 1u : 0u;
}

__device__ __forceinline__ bool iou_gt(float x1a, float y1a, float x2a, float y2a, float aA,
                                       float x1b, float y1b, float x2b, float y2b, float aB) {
    float iw = fminf(x2a, x2b) - fmaxf(x1a, x1b);
    float ih = fminf(y2a, y2b) - fmaxf(y1a, y1b);
    iw = fmaxf(iw, 0.0f);
    ih = fmaxf(ih, 0.0f);
    float inter = iw * ih;
    float iou = inter / (aA + aB - inter + 1e-8f);
    return iou > 0.3f;
}

__global__ __launch_bounds__(1024) void k_nms(const float* __restrict__ gx1, const float* __restrict__ gy1,
                      const float* __restrict__ gx2, const float* __restrict__ gy2,
                      const float* __restrict__ gar, const u32* __restrict__ valid,
                      float* __restrict__ out) {
    __shared__ float lx1[TOPK], ly1[TOPK], lx2[TOPK], ly2[TOPK], lar[TOPK];
    __shared__ unsigned char lkeep[TOPK];
    __shared__ u64 supmask[64];
    __shared__ u32 klist[64];
    __shared__ int km;
    int tid = threadIdx.x;
    for (int t = tid; t < TOPK; t += 1024) {
        lx1[t] = gx1[t]; ly1[t] = gy1[t]; lx2[t] = gx2[t]; ly2[t] = gy2[t];
        lar[t] = gar[t];
        lkeep[t] = (unsigned char)valid[t];
    }
    __syncthreads();
    for (int c0 = 0; c0 < TOPK; c0 += 64) {
        int nc = (TOPK - c0 < 64) ? (TOPK - c0) : 64;
        if (tid < 64) supmask[tid] = 0ull;
        __syncthreads();
        // pairwise within chunk: bit s of supmask[j] = iou(s,j)>T, s<j
        for (int t = tid; t < 64*64; t += 1024) {
            int s = t >> 6, j = t & 63;
            if (s < j && j < nc) {
                int A = c0 + s, B = c0 + j;
                if (iou_gt(lx1[A], ly1[A], lx2[A], ly2[A], lar[A],
                           lx1[B], ly1[B], lx2[B], ly2[B], lar[B]))
                    atomicOr(&supmask[j], 1ull << s);
            }
        }
        __syncthreads();
        // wave 0: sequential greedy cascade via ballots
        if (tid < 64) {
            int j = tid;
            bool alive = (j < nc) ? (lkeep[c0 + j] != 0) : false;
            u64 sm = supmask[j];
            u64 am = __ballot(alive);
            for (int s = 0; s < nc; ++s) {
                if ((am >> s) & 1ull) {
                    if ((sm >> s) & 1ull) alive = false;
                    am = __ballot(alive);
                }
            }
            if (j < nc) lkeep[c0 + j] = alive ? 1 : 0;
            u64 kmsk = __ballot(alive);
            if (alive) {
                int pos = __popcll(kmsk & ((1ull << j) - 1ull));
                klist[pos] = (u32)(c0 + j);
            }
            if (j == 0) km = __popcll(kmsk);
        }
        __syncthreads();
        // apply this chunk's kept boxes to all later boxes
        int m = km;
        for (int t = c0 + 64 + tid; t < TOPK; t += 1024) {
            if (!lkeep[t]) continue;
            for (int q = 0; q < m; ++q) {
                int A = (int)klist[q];
                if (iou_gt(lx1[A], ly1[A], lx2[A], ly2[A], lar[A],
                           lx1[t], ly1[t], lx2[t], ly2[t], lar[t])) {
                    lkeep[t] = 0; break;
                }
            }
        }
        __syncthreads();
    }
    for (int t = tid; t < TOPK; t += 1024) out[24000 + t] = lkeep[t] ? 1.0f : 0.0f;
}

extern "C" void kernel_launch(void* const* d_in, const int* in_sizes, int n_in,
                              void* d_out, int out_size, void* d_ws, size_t ws_size,
                              hipStream_t stream) {
    const float* obj  = (const float*)d_in[0];
    const float* reg  = (const float*)d_in[1];
    const float* anch = (const float*)d_in[2];
    float* out = (float*)d_out;
    char* ws = (char*)d_ws;

    u32* hist = (u32*)(ws + WS_HIST);
    u32* meta = (u32*)(ws + WS_META);
    u32* ckey = (u32*)(ws + WS_CKEY);
    u32* cidx = (u32*)(ws + WS_CIDX);
    u32* sel  = (u32*)(ws + WS_SEL);
    float* nx1 = (float*)(ws + WS_NX1);
    float* ny1 = (float*)(ws + WS_NY1);
    float* nx2 = (float*)(ws + WS_NX2);
    float* ny2 = (float*)(ws + WS_NY2);
    float* nar = (float*)(ws + WS_NAR);
    u32* valid = (u32*)(ws + WS_VAL);

    hipLaunchKernelGGL(k_zero, dim3((NBUCKET + 16 + 255) / 256), dim3(256), 0, stream, (u32*)ws);
    hipLaunchKernelGGL(k_hist, dim3(NPIX / 256), dim3(256), 0, stream, obj, hist);
    hipLaunchKernelGGL(k_scan, dim3(1), dim3(1024), 0, stream, hist, meta);
    hipLaunchKernelGGL(k_compact, dim3(NPIX / 256), dim3(256), 0, stream, obj, meta, ckey, cidx);
    hipLaunchKernelGGL(k_rank, dim3(64), dim3(256), 0, stream, meta, ckey, cidx, sel);
    hipLaunchKernelGGL(k_gather, dim3((TOPK + 255) / 256), dim3(256), 0, stream,
                       obj, reg, anch, sel, out, nx1, ny1, nx2, ny2, nar, valid);
    hipLaunchKernelGGL(k_nms, dim3(1), dim3(1024), 0, stream, nx1, ny1, nx2, ny2, nar, valid, out);
}

// Round 3
// 585.314 us; speedup vs baseline: 4.1523x; 4.1523x over previous
//
#include <hip/hip_runtime.h>
#include <cstdint>
#include <math.h>

#pragma clang fp contract(off)

typedef unsigned int u32;
typedef unsigned long long u64;

#define HFEAT 512
#define WFEAT 512
#define NPIX (HFEAT*WFEAT)          // 262144
#define TOPK 4000
#define IMG_SZ 16384.0f
#define NBUCKET 8192
#define CAP 32768

// ---- workspace layout (bytes) ----
#define WS_HIST 0                    // u32[8192]   32768
#define WS_META 32768                // u32[16]     64
#define WS_CKEY 32832                // u32[CAP]    131072
#define WS_CIDX 163904               // u32[CAP]    131072
#define WS_SEL  294976               // u32[TOPK]   16000
#define WS_NX1  310976               // f32[TOPK]
#define WS_NY1  326976
#define WS_NX2  342976
#define WS_NY2  358976
#define WS_NAR  374976
#define WS_VAL  390976               // u32[TOPK] -> 406976
#define WS_MASK 409600               // u64[4000*64] = 2,048,000 -> end 2,457,600
#define WS_END_FAST (WS_MASK + (size_t)TOPK*64*8)

// f32 softmax over 2 logits, replicating numpy float32 op-for-op.
__device__ __forceinline__ void softmax2(float l0, float l1, float& s0, float& s1) {
    float m = fmaxf(l0, l1);
    float a0 = l0 - m;
    float a1 = l1 - m;
    float e0 = (float)::exp((double)a0);
    float e1 = (float)::exp((double)a1);
    float den = e0 + e1;
    s0 = e0 / den;
    s1 = e1 / den;
}

__global__ void k_zero(u32* ws32) {
    int t = blockIdx.x * blockDim.x + threadIdx.x;
    if (t < NBUCKET + 16) ws32[t] = 0;
}

// histogram of f32 score bits for score > 0.5; bucket = (bits - 0x3F000000) >> 10
__global__ void k_hist(const float* __restrict__ obj, u32* __restrict__ hist) {
    __shared__ u32 lh[NBUCKET];
    int tid = threadIdx.x;
    for (int b = tid; b < NBUCKET; b += 256) lh[b] = 0;
    __syncthreads();
    int p = blockIdx.x * 256 + tid;
    const float* o = obj + (size_t)p * 18;
#pragma unroll
    for (int k = 0; k < 9; ++k) {
        float s0, s1;
        softmax2(o[2*k], o[2*k+1], s0, s1);
        if (s1 > 0.5f) {
            u32 b = (__float_as_uint(s1) - 0x3F000000u) >> 10;
            atomicAdd(&lh[b], 1u);
        }
    }
    __syncthreads();
    for (int b = tid; b < NBUCKET; b += 256) {
        u32 c = lh[b];
        if (c) atomicAdd(&hist[b], c);
    }
}

// find threshold bucket: smallest B with count(bucket >= B) >= TOPK
__global__ void k_scan(const u32* __restrict__ hist, u32* __restrict__ meta) {
    __shared__ u32 ss[1024];
    int t = threadIdx.x;
    u32 local = 0;
#pragma unroll
    for (int j = 0; j < 8; ++j) local += hist[t*8 + j];
    ss[t] = local;
    __syncthreads();
    for (int off = 1; off < 1024; off <<= 1) {
        u32 v = (t + off < 1024) ? ss[t + off] : 0;
        __syncthreads();
        ss[t] += v;
        __syncthreads();
    }
    u32 S_t = ss[t];
    u32 S_next = (t < 1023) ? ss[t+1] : 0;
    if (S_t >= TOPK && S_next < TOPK) {
        u32 cum = S_next;
        int bsel = t*8;
        for (int b = t*8 + 7; b >= t*8; --b) {
            cum += hist[b];
            if (cum >= TOPK) { bsel = b; break; }
        }
        meta[1] = (u32)bsel;
        meta[2] = cum;
    }
}

__global__ void k_compact(const float* __restrict__ obj, u32* __restrict__ meta,
                          u32* __restrict__ ckey, u32* __restrict__ cidx) {
    int p = blockIdx.x * 256 + threadIdx.x;
    u32 thr = 0x3F000000u + (meta[1] << 10);
    const float* o = obj + (size_t)p * 18;
#pragma unroll
    for (int k = 0; k < 9; ++k) {
        float s0, s1;
        softmax2(o[2*k], o[2*k+1], s0, s1);
        if (s1 > 0.5f) {
            u32 bits = __float_as_uint(s1);
            if (bits >= thr) {
                u32 pos = atomicAdd(&meta[0], 1u);
                if (pos < CAP) { ckey[pos] = bits; cidx[pos] = (u32)(p*9 + k); }
            }
        }
    }
}

#define RTILE 4096
// exact rank of each candidate: (score desc, idx asc); ranks form a permutation
__global__ void k_rank(const u32* __restrict__ meta, const u32* __restrict__ ckey,
                       const u32* __restrict__ cidx, u32* __restrict__ sel) {
    __shared__ u32 lk[RTILE];
    __shared__ u32 li[RTILE];
    int tid = threadIdx.x;
    u32 Mu = meta[0];
    int M = (int)(Mu < (u32)CAP ? Mu : (u32)CAP);
    for (int cb = blockIdx.x * 256; cb < M; cb += gridDim.x * 256) {
        int c = cb + tid;
        bool act = (c < M);
        u32 key = 0, idx = 0;
        if (act) { key = ckey[c]; idx = cidx[c]; }
        int rank = 0;
        for (int t0 = 0; t0 < M; t0 += RTILE) {
            int cnt = (M - t0 < RTILE) ? (M - t0) : RTILE;
            __syncthreads();
            for (int j = tid; j < cnt; j += 256) { lk[j] = ckey[t0+j]; li[j] = cidx[t0+j]; }
            __syncthreads();
            if (act) {
                for (int j = 0; j < cnt; ++j) {
                    u32 kj = lk[j];
                    rank += (kj > key || (kj == key && li[j] < idx)) ? 1 : 0;
                }
            }
        }
        if (act && rank < TOPK) sel[rank] = idx;
    }
}

__global__ void k_gather(const float* __restrict__ obj, const float* __restrict__ reg,
                         const float* __restrict__ anch, const u32* __restrict__ sel,
                         float* __restrict__ out,
                         float* __restrict__ nx1, float* __restrict__ ny1,
                         float* __restrict__ nx2, float* __restrict__ ny2,
                         float* __restrict__ nar, u32* __restrict__ valid) {
    int r = blockIdx.x * 256 + threadIdx.x;
    if (r >= TOPK) return;
    u32 i = sel[r];
    u32 p = i / 9u, k = i - p * 9u;
    float l0 = obj[(size_t)p*18 + 2*k];
    float l1 = obj[(size_t)p*18 + 2*k + 1];
    float s0, s1;
    softmax2(l0, l1, s0, s1);
    const float* rg = reg + (size_t)p*36 + 4*k;
    float t0 = rg[0], t1 = rg[1], t2 = rg[2], t3 = rg[3];
    const float* an = anch + (size_t)i*4;
    float a0 = an[0], a1 = an[1], a2 = an[2], a3 = an[3];
    float cx = a0 + a2/2.0f + t0*a2;
    float cy = a1 + a3/2.0f + t1*a3;
    float w = a2 * (float)::exp((double)t2);
    float h = a3 * (float)::exp((double)t3);
    float bx = cx - w/2.0f;
    float by = cy - h/2.0f;
    float x1 = fminf(fmaxf(bx, 0.0f), IMG_SZ);
    float y1 = fminf(fmaxf(by, 0.0f), IMG_SZ);
    float x2 = fminf(fmaxf(bx + w, 0.0f), IMG_SZ);
    float y2 = fminf(fmaxf(by + h, 0.0f), IMG_SZ);
    float bw = x2 - x1, bh = y2 - y1;
    out[4*r+0] = x1;
    out[4*r+1] = y1;
    out[4*r+2] = bw;
    out[4*r+3] = bh;
    out[16000 + 2*r]     = s0;
    out[16000 + 2*r + 1] = s1;
    nx1[r] = x1; ny1[r] = y1;
    nx2[r] = x1 + bw;
    ny2[r] = y1 + bh;
    nar[r] = bw * bh;
    valid[r] = (s1 > 0.5f) ? 1u : 0u;
}

__device__ __forceinline__ bool iou_gt(float x1a, float y1a, float x2a, float y2a, float aA,
                                       float x1b, float y1b, float x2b, float y2b, float aB) {
    float iw = fminf(x2a, x2b) - fmaxf(x1a, x1b);
    float ih = fminf(y2a, y2b) - fmaxf(y1a, y1b);
    iw = fmaxf(iw, 0.0f);
    ih = fmaxf(ih, 0.0f);
    float inter = iw * ih;
    float iou = inter / (aA + aB - inter + 1e-8f);
    return iou > 0.3f;
}

// ---- fast NMS path: full suppression bitmask, built grid-wide ----
// mask[i*64 + w] bit b: box i suppresses box j=w*64+b (j>i, iou>T)
__global__ void k_mask(const float* __restrict__ nx1, const float* __restrict__ ny1,
                       const float* __restrict__ nx2, const float* __restrict__ ny2,
                       const float* __restrict__ nar, u64* __restrict__ mask) {
    __shared__ float cx1[64], cy1[64], cx2[64], cy2[64], car[64];
    int w = blockIdx.y;
    int j0 = w * 64;
    int tid = threadIdx.x;
    if (tid < 64) {
        int j = j0 + tid;
        bool v = j < TOPK;
        cx1[tid] = v ? nx1[j] : 1e9f;
        cy1[tid] = v ? ny1[j] : 1e9f;
        cx2[tid] = v ? nx2[j] : 1e9f;
        cy2[tid] = v ? ny2[j] : 1e9f;
        car[tid] = v ? nar[j] : 0.f;
    }
    __syncthreads();
    int i = blockIdx.x * 256 + tid;
    if (i >= TOPK) return;
    float x1 = nx1[i], y1 = ny1[i], x2 = nx2[i], y2 = ny2[i], ar = nar[i];
    u64 bits = 0;
#pragma unroll
    for (int b = 0; b < 64; ++b) {
        int j = j0 + b;
        if (j < TOPK && j > i &&
            iou_gt(x1, y1, x2, y2, ar, cx1[b], cy1[b], cx2[b], cy2[b], car[b]))
            bits |= (1ull << b);
    }
    mask[(size_t)i * 64 + w] = bits;
}

// single block: wave 0 walks boxes in order over the bitmask; waves 1..15 prefetch
__global__ __launch_bounds__(1024) void k_scan_nms(const u64* __restrict__ mask,
                                                   const u32* __restrict__ valid,
                                                   float* __restrict__ out) {
    __shared__ u64 buf[2][64 * 64];
    __shared__ u64 keep_s[64];
    int tid = threadIdx.x;
    int wave = tid >> 6, lane = tid & 63;
    u64 kw = 0;
    if (wave == 0) {
        for (int b = 0; b < 64; ++b) {
            int t = lane * 64 + b;
            u32 v = (t < TOPK) ? valid[t] : 0u;
            kw |= ((u64)(v & 1u)) << b;
        }
    }
    // load batch 0 (rows 0..63)
    for (int q = tid; q < 64 * 64; q += 1024) {
        buf[0][q] = mask[q];   // row r word wd at r*64+wd == q
    }
    __syncthreads();
    const int NB = (TOPK + 63) / 64;   // 63
    for (int g = 0; g < NB; ++g) {
        int cur = g & 1;
        if (wave != 0) {
            int gn = g + 1;
            if (gn < NB) {
                for (int q = tid - 64; q < 64 * 64; q += 960) {
                    int r = q >> 6, wd = q & 63;
                    int row = gn * 64 + r;
                    buf[gn & 1][q] = (row < TOPK) ? mask[(size_t)row * 64 + wd] : 0ull;
                }
            }
        } else {
            u64 wg = __shfl(kw, g);
            int rmax = (TOPK - g * 64 < 64) ? (TOPK - g * 64) : 64;
            for (int r = 0; r < rmax; ++r) {
                if ((wg >> r) & 1ull) {
                    u64 m = buf[cur][r * 64 + lane];
                    kw &= ~m;
                    u64 mg = __shfl(m, g);
                    wg &= ~mg;
                }
            }
        }
        __syncthreads();
    }
    if (wave == 0) keep_s[lane] = kw;
    __syncthreads();
    for (int t = tid; t < TOPK; t += 1024)
        out[24000 + t] = ((keep_s[t >> 6] >> (t & 63)) & 1ull) ? 1.0f : 0.0f;
}

// ---- fallback single-block NMS (used if ws too small for the mask) ----
__global__ __launch_bounds__(1024) void k_nms(const float* __restrict__ gx1, const float* __restrict__ gy1,
                      const float* __restrict__ gx2, const float* __restrict__ gy2,
                      const float* __restrict__ gar, const u32* __restrict__ valid,
                      float* __restrict__ out) {
    __shared__ float lx1[TOPK], ly1[TOPK], lx2[TOPK], ly2[TOPK], lar[TOPK];
    __shared__ unsigned char lkeep[TOPK];
    __shared__ u64 supmask[64];
    __shared__ u32 klist[64];
    __shared__ int km;
    int tid = threadIdx.x;
    for (int t = tid; t < TOPK; t += 1024) {
        lx1[t] = gx1[t]; ly1[t] = gy1[t]; lx2[t] = gx2[t]; ly2[t] = gy2[t];
        lar[t] = gar[t];
        lkeep[t] = (unsigned char)valid[t];
    }
    __syncthreads();
    for (int c0 = 0; c0 < TOPK; c0 += 64) {
        int nc = (TOPK - c0 < 64) ? (TOPK - c0) : 64;
        if (tid < 64) supmask[tid] = 0ull;
        __syncthreads();
        for (int t = tid; t < 64*64; t += 1024) {
            int s = t >> 6, j = t & 63;
            if (s < j && j < nc) {
                int A = c0 + s, B = c0 + j;
                if (iou_gt(lx1[A], ly1[A], lx2[A], ly2[A], lar[A],
                           lx1[B], ly1[B], lx2[B], ly2[B], lar[B]))
                    atomicOr(&supmask[j], 1ull << s);
            }
        }
        __syncthreads();
        if (tid < 64) {
            int j = tid;
            bool alive = (j < nc) ? (lkeep[c0 + j] != 0) : false;
            u64 sm = supmask[j];
            u64 am = __ballot(alive);
            for (int s = 0; s < nc; ++s) {
                if ((am >> s) & 1ull) {
                    if ((sm >> s) & 1ull) alive = false;
                    am = __ballot(alive);
                }
            }
            if (j < nc) lkeep[c0 + j] = alive ? 1 : 0;
            u64 kmsk = __ballot(alive);
            if (alive) {
                int pos = __popcll(kmsk & ((1ull << j) - 1ull));
                klist[pos] = (u32)(c0 + j);
            }
            if (j == 0) km = __popcll(kmsk);
        }
        __syncthreads();
        int m = km;
        for (int t = c0 + 64 + tid; t < TOPK; t += 1024) {
            if (!lkeep[t]) continue;
            for (int q = 0; q < m; ++q) {
                int A = (int)klist[q];
                if (iou_gt(lx1[A], ly1[A], lx2[A], ly2[A], lar[A],
                           lx1[t], ly1[t], lx2[t], ly2[t], lar[t])) {
                    lkeep[t] = 0; break;
                }
            }
        }
        __syncthreads();
    }
    for (int t = tid; t < TOPK; t += 1024) out[24000 + t] = lkeep[t] ? 1.0f : 0.0f;
}

extern "C" void kernel_launch(void* const* d_in, const int* in_sizes, int n_in,
                              void* d_out, int out_size, void* d_ws, size_t ws_size,
                              hipStream_t stream) {
    const float* obj  = (const float*)d_in[0];
    const float* reg  = (const float*)d_in[1];
    const float* anch = (const float*)d_in[2];
    float* out = (float*)d_out;
    char* ws = (char*)d_ws;

    u32* hist = (u32*)(ws + WS_HIST);
    u32* meta = (u32*)(ws + WS_META);
    u32* ckey = (u32*)(ws + WS_CKEY);
    u32* cidx = (u32*)(ws + WS_CIDX);
    u32* sel  = (u32*)(ws + WS_SEL);
    float* nx1 = (float*)(ws + WS_NX1);
    float* ny1 = (float*)(ws + WS_NY1);
    float* nx2 = (float*)(ws + WS_NX2);
    float* ny2 = (float*)(ws + WS_NY2);
    float* nar = (float*)(ws + WS_NAR);
    u32* valid = (u32*)(ws + WS_VAL);
    u64* mask  = (u64*)(ws + WS_MASK);

    hipLaunchKernelGGL(k_zero, dim3((NBUCKET + 16 + 255) / 256), dim3(256), 0, stream, (u32*)ws);
    hipLaunchKernelGGL(k_hist, dim3(NPIX / 256), dim3(256), 0, stream, obj, hist);
    hipLaunchKernelGGL(k_scan, dim3(1), dim3(1024), 0, stream, hist, meta);
    hipLaunchKernelGGL(k_compact, dim3(NPIX / 256), dim3(256), 0, stream, obj, meta, ckey, cidx);
    hipLaunchKernelGGL(k_rank, dim3(64), dim3(256), 0, stream, meta, ckey, cidx, sel);
    hipLaunchKernelGGL(k_gather, dim3((TOPK + 255) / 256), dim3(256), 0, stream,
                       obj, reg, anch, sel, out, nx1, ny1, nx2, ny2, nar, valid);
    if (ws_size >= WS_END_FAST) {
        hipLaunchKernelGGL(k_mask, dim3((TOPK + 255) / 256, 64), dim3(256), 0, stream,
                           nx1, ny1, nx2, ny2, nar, mask);
        hipLaunchKernelGGL(k_scan_nms, dim3(1), dim3(1024), 0, stream, mask, valid, out);
    } else {
        hipLaunchKernelGGL(k_nms, dim3(1), dim3(1024), 0, stream, nx1, ny1, nx2, ny2, nar, valid, out);
    }
}